// Round 4
// baseline (13023.105 us; speedup 1.0000x reference)
//
#include <hip/hip_runtime.h>
#include <math.h>

#define NB 256
#define NN 512
#define NT 1024
#define SINK_ITERS 50
#define EPSF 1e-10f
#define LOG2E 1.4426950408889634f
#define RPAD 514   // padded row stride (words): rotates banks by 2*row -> no 32-way conflicts

__device__ __forceinline__ float hexp2(float x) { return __builtin_amdgcn_exp2f(x); }
__device__ __forceinline__ float hlog2(float x) { return __builtin_amdgcn_logf(x); }

// One block (1024 threads) per batch row. Thread (ti,tj) owns the 16x16 tile
// rows i = ti*16+a, cols j = tj*16+b of the 512x512 Sinkhorn matrix, held in
// registers as float2 E[16][8] (pairs along b). Phases: E *= scale; sum tiles;
// cross-tile reduce via red2d[32][RPAD] in LDS. Linear domain == reference.
__global__ __launch_bounds__(NT, 4) void ndcg_main_kernel(const float* __restrict__ y_pred,
                                                          const float* __restrict__ y_true,
                                                          float* __restrict__ ws)
{
    const int b  = blockIdx.x;
    const int t  = threadIdx.x;
    const int ti = t >> 5;          // tile-row 0..31
    const int tj = t & 31;          // tile-col 0..31
    const int i0 = ti * 16;
    const int j0 = tj * 16;

    __shared__ __align__(16) float  red2d[32][RPAD];  // 65.8 KB partials
    __shared__ __align__(16) float2 pkJ2[NN];         // {sL_j, Vl_j}
    __shared__ __align__(16) float  mneg[NN];         // -rowmax_i
    __shared__ __align__(16) float  scl[NN];          // per-phase scale factors
    __shared__ __align__(16) float  gls[NN];          // gains 2^yt - 1
    __shared__ __align__(16) float  sS[NN];
    __shared__ __align__(16) float  red[NT];
    __shared__ float resA;
    __shared__ int   hist[5];

    // ---------------- pass 0: loads, histogram, R_j, gains, idcg ----------------
    float yt = 0.f, s = 0.f, disc = 0.f, idcg_term = 0.f;
    if (t < NN) { s = y_pred[b * NN + t]; yt = y_true[b * NN + t]; sS[t] = s; }
    if (t < 5) hist[t] = 0;
    __syncthreads();
    if (t < NN) {
        int vi = (int)(yt + 0.5f);
        vi = vi < 0 ? 0 : (vi > 4 ? 4 : vi);
        atomicAdd(&hist[vi], 1);
        gls[t] = hexp2(yt) - 1.0f;
    }
    const int e = t & (NN - 1), h = t >> 9;
    const float se = sS[e];
    const float4* sS4 = (const float4*)sS;
    float Rp = 0.f;
#pragma unroll 8
    for (int m = h * (NN / 8); m < (h + 1) * (NN / 8); ++m) {
        float4 f = sS4[m];
        Rp += fabsf(se - f.x) + fabsf(se - f.y) + fabsf(se - f.z) + fabsf(se - f.w);
    }
    red[t] = Rp;
    __syncthreads();                       // covers hist atomics + gls writes
    if (h == 0) {
        float R = red[t] + red[t + NN];
        pkJ2[e] = make_float2(se * LOG2E, -R * LOG2E);
        disc = 1.0f / hlog2((float)e + 2.0f);
        int c4 = hist[4];
        int c3 = c4 + hist[3];
        int c2 = c3 + hist[2];
        int c1 = c2 + hist[1];
        float gp = (e < c4) ? 15.f : (e < c3) ? 7.f : (e < c2) ? 3.f :
                   (e < c1) ? 1.f : 0.f;
        idcg_term = gp * disc;
    }
    __syncthreads();

    // per-thread column data {sL_j, Vl_j} for its 16 cols
    float2 cj[16];
#pragma unroll
    for (int bq = 0; bq < 16; ++bq) cj[bq] = pkJ2[j0 + bq];

    // ---------------- pass A: row maxes (log2 domain) ----------------
    float mp[16];
#pragma unroll
    for (int a = 0; a < 16; ++a) {
        float sc = 511.0f - 2.0f * (float)(i0 + a);
        float mm = -3.4e38f;
#pragma unroll
        for (int bq = 0; bq < 16; ++bq)
            mm = fmaxf(mm, fmaf(sc, cj[bq].x, cj[bq].y));
        mp[a] = mm;
    }
#pragma unroll
    for (int aa = 0; aa < 8; ++aa)
        *(float2*)&red2d[tj][i0 + 2 * aa] = make_float2(mp[2 * aa], mp[2 * aa + 1]);
    __syncthreads();
    if (t < NN) {
        float mm = -3.4e38f;
#pragma unroll
        for (int k = 0; k < 32; ++k) mm = fmaxf(mm, red2d[k][t]);
        mneg[t] = -mm;
    }
    __syncthreads();

    // ---------------- pass B: materialize E = exp2(a_ij - m_i), Z partials ----------------
    float2 E[16][8];
    {
        float zp[16];
#pragma unroll
        for (int a = 0; a < 16; ++a) {
            float sc = 511.0f - 2.0f * (float)(i0 + a);
            float mg = mneg[i0 + a];
            float z = 0.f;
#pragma unroll
            for (int bb = 0; bb < 8; ++bb) {
                float ex = hexp2(fmaf(sc, cj[2 * bb].x,     cj[2 * bb].y)     + mg);
                float ey = hexp2(fmaf(sc, cj[2 * bb + 1].x, cj[2 * bb + 1].y) + mg);
                E[a][bb] = make_float2(ex, ey);
                z += ex + ey;
            }
            zp[a] = z;
        }
#pragma unroll
        for (int aa = 0; aa < 8; ++aa)
            *(float2*)&red2d[tj][i0 + 2 * aa] = make_float2(zp[2 * aa], zp[2 * aa + 1]);
    }
    __syncthreads();
    if (t < NN) {
        float z = 0.f;
#pragma unroll
        for (int k = 0; k < 32; ++k) z += red2d[k][t];
        scl[t] = 1.0f / z;                 // softmax row normalizer (z >= 1)
    }
    __syncthreads();

    // pending row scales
    float p[16];
#pragma unroll
    for (int aa = 0; aa < 8; ++aa) {
        float2 v = *(const float2*)&scl[i0 + 2 * aa];
        p[2 * aa] = v.x; p[2 * aa + 1] = v.y;
    }

    // ---------------- Sinkhorn: 50 x { col-normalize, row-normalize } ----------------
    for (int it = 0; it < SINK_ITERS; ++it) {
        // col phase: apply pending row scales, accumulate column partials
        float2 cp[8];
#pragma unroll
        for (int bb = 0; bb < 8; ++bb) cp[bb] = make_float2(0.f, 0.f);
#pragma unroll
        for (int a = 0; a < 16; ++a) {
            float r = p[a];
#pragma unroll
            for (int bb = 0; bb < 8; ++bb) {
                float ex = E[a][bb].x * r;
                float ey = E[a][bb].y * r;
                E[a][bb] = make_float2(ex, ey);
                cp[bb].x += ex;
                cp[bb].y += ey;
            }
        }
#pragma unroll
        for (int bb = 0; bb < 8; ++bb)
            *(float2*)&red2d[ti][j0 + 2 * bb] = cp[bb];
        __syncthreads();
        if (t < NN) {
            float cs = 0.f;
#pragma unroll
            for (int k = 0; k < 32; ++k) cs += red2d[k][t];
            scl[t] = 1.0f / fmaxf(cs, EPSF);
        }
        __syncthreads();

        // row phase: apply col scales, accumulate row partials
        float2 g2[8];
#pragma unroll
        for (int bb = 0; bb < 8; ++bb) g2[bb] = *(const float2*)&scl[j0 + 2 * bb];
        float2 ra[16];
#pragma unroll
        for (int a = 0; a < 16; ++a) {
            float ax = 0.f, ay = 0.f;
#pragma unroll
            for (int bb = 0; bb < 8; ++bb) {
                float ex = E[a][bb].x * g2[bb].x;
                float ey = E[a][bb].y * g2[bb].y;
                E[a][bb] = make_float2(ex, ey);
                ax += ex;
                ay += ey;
            }
            ra[a] = make_float2(ax, ay);
        }
#pragma unroll
        for (int aa = 0; aa < 8; ++aa)
            *(float2*)&red2d[tj][i0 + 2 * aa] =
                make_float2(ra[2 * aa].x + ra[2 * aa].y, ra[2 * aa + 1].x + ra[2 * aa + 1].y);
        __syncthreads();
        if (t < NN) {
            float rs = 0.f;
#pragma unroll
            for (int k = 0; k < 32; ++k) rs += red2d[k][t];
            scl[t] = 1.0f / fmaxf(rs, EPSF);
        }
        __syncthreads();
#pragma unroll
        for (int aa = 0; aa < 8; ++aa) {
            float2 v = *(const float2*)&scl[i0 + 2 * aa];
            p[2 * aa] = v.x; p[2 * aa + 1] = v.y;
        }
    }

    // ---------------- epilogue: gt_i = p_i * sum_j E_ij * g_j ----------------
    {
        float2 gg[8];
#pragma unroll
        for (int bb = 0; bb < 8; ++bb) gg[bb] = *(const float2*)&gls[j0 + 2 * bb];
        float gp[16];
#pragma unroll
        for (int a = 0; a < 16; ++a) {
            float ax = 0.f, ay = 0.f;
#pragma unroll
            for (int bb = 0; bb < 8; ++bb) {
                ax = fmaf(E[a][bb].x, gg[bb].x, ax);
                ay = fmaf(E[a][bb].y, gg[bb].y, ay);
            }
            gp[a] = p[a] * (ax + ay);
        }
#pragma unroll
        for (int aa = 0; aa < 8; ++aa)
            *(float2*)&red2d[tj][i0 + 2 * aa] = make_float2(gp[2 * aa], gp[2 * aa + 1]);
    }
    __syncthreads();
    float term = 0.f;
    if (t < NN) {
        float gt = 0.f;
#pragma unroll
        for (int k = 0; k < 32; ++k) gt += red2d[k][t];
        term = gt * disc;
    }
    red[t] = term;                         // 0 for t >= NN
    __syncthreads();
    for (int st = NT / 2; st > 0; st >>= 1) {
        if (t < st) red[t] += red[t + st];
        __syncthreads();
    }
    if (t == 0) resA = red[0];
    __syncthreads();
    red[t] = idcg_term;                    // 0 for t >= NN
    __syncthreads();
    for (int st = NT / 2; st > 0; st >>= 1) {
        if (t < st) red[t] += red[t + st];
        __syncthreads();
    }
    if (t == 0) {
        float idcg = red[0];
        bool ok = (idcg != 0.0f);
        ws[2 * b + 0] = ok ? resA / (idcg + EPSF) : 0.f;
        ws[2 * b + 1] = ok ? 1.f : 0.f;
    }
}

__global__ __launch_bounds__(NB) void ndcg_finalize_kernel(const float* __restrict__ ws,
                                                           float* __restrict__ out) {
    const int t = threadIdx.x;
    __shared__ float rn[NB];
    __shared__ float rc[NB];
    rn[t] = ws[2 * t + 0];
    rc[t] = ws[2 * t + 1];
    __syncthreads();
    for (int st = NB / 2; st > 0; st >>= 1) {
        if (t < st) { rn[t] += rn[t + st]; rc[t] += rc[t + st]; }
        __syncthreads();
    }
    if (t == 0) out[0] = -rn[0] / rc[0];
}

extern "C" void kernel_launch(void* const* d_in, const int* in_sizes, int n_in,
                              void* d_out, int out_size, void* d_ws, size_t ws_size,
                              hipStream_t stream) {
    const float* y_pred = (const float*)d_in[0];
    const float* y_true = (const float*)d_in[1];
    float* out = (float*)d_out;
    float* ws  = (float*)d_ws;

    ndcg_main_kernel<<<NB, NT, 0, stream>>>(y_pred, y_true, ws);
    ndcg_finalize_kernel<<<1, NB, 0, stream>>>(ws, out);
}

// Round 5
// 487.485 us; speedup vs baseline: 26.7149x; 26.7149x over previous
//
#include <hip/hip_runtime.h>
#include <math.h>

#define NB 256
#define NN 512
#define NT 1024
#define SINK_ITERS 50
#define EPSF 1e-10f
#define LOG2E 1.4426950408889634f
#define RPAD 516

__device__ __forceinline__ float hexp2(float x) { return __builtin_amdgcn_exp2f(x); }
__device__ __forceinline__ float hlog2(float x) { return __builtin_amdgcn_logf(x); }

// padded index for the per-column float4 table {x, lx, lb, lgain}
__device__ __forceinline__ int xidx(int j) { return j + (j >> 4); }

struct Shm {
    __align__(16) float  red2d[32][RPAD];  // 66 KB cross-tile partials
    __align__(16) float4 x4p[NN + 32];     // per-col {x_j, lx_j, lb_j, lgain_j}, padded idx
    __align__(16) float  laS[NN];          // row log-scales la_i
    __align__(16) float  wS[NN];           // col-phase chunk-centered coefficients
    __align__(16) float  red[NT];
    __align__(16) float  sS[NN];
    int   cint[128];                       // 4-row-group centering (int exponents)
    int   ccint[64];                       // 8-coef-chunk centering (col phase)
    int   hist[5];
    float resA;
};

// State invariant: M_ij = exp2(la_i + lb_j + i*lx_j).
// Row phase: T_i = sum_j exp2(lb_j (+lgain_j) + i*lx_j); la_i = -log2(T_i)  (or epilogue term).
template<bool UPDLA, bool ADDG>
__device__ __forceinline__ void row_phase(Shm& sh, int t, float disc, float* termOut) {
    const int cg = t & 31;                 // column group: j in [16cg, 16cg+16)
    const int rc = t >> 5;                 // row chunk:   i in [16rc, 16rc+16)
    const int r0 = rc * 4;
    const float i0f = (float)(rc * 16);

    const int c0 = sh.cint[r0], c1 = sh.cint[r0 + 1],
              c2 = sh.cint[r0 + 2], c3 = sh.cint[r0 + 3];

    float q[16], xv[16];
#pragma unroll
    for (int c = 0; c < 16; ++c) {
        float4 p = sh.x4p[17 * cg + c];
        float lq = fmaf(i0f, p.y, p.z) - (float)c0;
        if (ADDG) lq += p.w;
        lq = fminf(lq, 126.f);             // inf guard (unreachable by bounds)
        q[c] = hexp2(lq);
        xv[c] = p.x;
    }

    float4 sbuf;
#pragma unroll
    for (int r = 0; r < 16; ++r) {
        float s0 = (q[0] + q[1]) + (q[2] + q[3]);
        float s1 = (q[4] + q[5]) + (q[6] + q[7]);
        float s2 = (q[8] + q[9]) + (q[10] + q[11]);
        float s3 = (q[12] + q[13]) + (q[14] + q[15]);
        float sr = (s0 + s1) + (s2 + s3);
        ((float*)&sbuf)[r & 3] = sr;
        if ((r & 3) == 3)
            *(float4*)&sh.red2d[cg][rc * 16 + (r & ~3)] = sbuf;
        if (r < 15) {
#pragma unroll
            for (int c = 0; c < 16; ++c) q[c] *= xv[c];
            if (r == 3) {
                const int d = c0 - c1;
#pragma unroll
                for (int c = 0; c < 16; ++c) q[c] = ldexpf(q[c], d);
            }
            if (r == 7) {
                const int d = c1 - c2;
#pragma unroll
                for (int c = 0; c < 16; ++c) q[c] = ldexpf(q[c], d);
            }
            if (r == 11) {
                const int d = c2 - c3;
#pragma unroll
                for (int c = 0; c < 16; ++c) q[c] = ldexpf(q[c], d);
            }
        }
    }
    __syncthreads();
    if (t < NN) {
        float T = 0.f;
#pragma unroll
        for (int k = 0; k < 32; ++k) T += sh.red2d[k][t];
        float lT = hlog2(T) + (float)sh.cint[t >> 2];
        if (UPDLA) {
            sh.laS[t] = -lT;
            if ((t & 3) == 0) sh.cint[t >> 2] = (int)rintf(lT);  // same-wave lockstep: reads above precede
        } else {
            *termOut = hexp2(sh.laS[t] + lT) * disc;
        }
    }
    __syncthreads();
}

// Col phase: P(x_j) = sum_i exp2(la_i) x_j^i via chunked Horner with (mant,exp) accumulator.
__device__ __forceinline__ void col_phase(Shm& sh, int t, float cx, float x8m, int ex8, float clx) {
    const int jc = t & (NN - 1);
    const int hc = t >> 9;

    if (t < NN) {                          // chunk-centered coefficients
        const int ch = t >> 3, b8 = ch << 3;
        float mx = sh.laS[b8];
#pragma unroll
        for (int k = 1; k < 8; ++k) mx = fmaxf(mx, sh.laS[b8 + k]);
        const int cci = (int)rintf(mx);
        sh.wS[t] = hexp2(sh.laS[t] - (float)cci);
        if ((t & 7) == 0) sh.ccint[ch] = cci;
    }
    __syncthreads();

    float A = 0.f;
    int   E = -(1 << 30);
    const int cb = hc * 256;
#pragma unroll 4
    for (int c = 31; c >= 0; --c) {
        const float4 w0 = *(const float4*)&sh.wS[cb + c * 8];
        const float4 w1 = *(const float4*)&sh.wS[cb + c * 8 + 4];
        float h = w1.w;
        h = fmaf(h, cx, w1.z); h = fmaf(h, cx, w1.y); h = fmaf(h, cx, w1.x);
        h = fmaf(h, cx, w0.w); h = fmaf(h, cx, w0.z); h = fmaf(h, cx, w0.y);
        h = fmaf(h, cx, w0.x);
        const int cc = sh.ccint[hc * 32 + c];
        const int eP = E + ex8;
        const int base = (eP > cc) ? eP : cc;
        float An = ldexpf(A * x8m, eP - base) + ldexpf(h, cc - base);
        An = (An < 1e-30f) ? 0.f : An;     // flush denormals
        const unsigned bb = __float_as_uint(An);
        const int en = (int)(bb >> 23) - 127;
        const float mn = __uint_as_float((bb & 0x007FFFFFu) | 0x3F800000u);
        const bool z = (An == 0.f);
        A = z ? 0.f : mn;
        E = z ? E : (base + en);
    }
    float lV = hlog2(A) + (float)E;        // A==0 -> -inf
    if (hc) lV = fmaf(256.f, clx, lV);
    sh.red[jc + NN * hc] = lV;
    __syncthreads();
    if (t < NN) {
        const float a = sh.red[t], b2 = sh.red[t + NN];
        const float L = fmaxf(a, b2), S = fminf(a, b2);
        float lb = (L < -1e30f) ? 0.f : -(L + hlog2(1.f + hexp2(S - L)));
        sh.x4p[xidx(t)].z = lb;
    }
    __syncthreads();
}

__global__ __launch_bounds__(NT) void ndcg_main_kernel(const float* __restrict__ y_pred,
                                                       const float* __restrict__ y_true,
                                                       float* __restrict__ ws) {
    __shared__ Shm sh;
    const int b = blockIdx.x;
    const int t = threadIdx.x;
    const int e = t & (NN - 1);
    const int hh = t >> 9;

    // ---- pass 0: loads, histogram, R_j, per-column table, idcg ----
    float yt = 0.f, s = 0.f, disc = 0.f, idcg_term = 0.f;
    if (t < NN) { s = y_pred[b * NN + t]; yt = y_true[b * NN + t]; sh.sS[t] = s; }
    if (t < 5) sh.hist[t] = 0;
    __syncthreads();
    if (t < NN) {
        int vi = (int)(yt + 0.5f);
        vi = vi < 0 ? 0 : (vi > 4 ? 4 : vi);
        atomicAdd(&sh.hist[vi], 1);
    }
    const float se = sh.sS[e];
    const float4* sS4 = (const float4*)sh.sS;
    float Rp = 0.f;
#pragma unroll 8
    for (int m = hh * (NN / 8); m < (hh + 1) * (NN / 8); ++m) {
        float4 f = sS4[m];
        Rp += fabsf(se - f.x) + fabsf(se - f.y) + fabsf(se - f.z) + fabsf(se - f.w);
    }
    sh.red[t] = Rp;
    __syncthreads();                        // covers hist atomics
    if (hh == 0) {
        const float R = sh.red[t] + sh.red[t + NN];
        const float sL = se * LOG2E;
        const float lx = -2.f * sL;
        float4 px;
        px.x = hexp2(lx);                   // x_j
        px.y = lx;                          // log2 x_j
        px.z = fmaf(511.f, sL, -R * LOG2E); // ld_j (initial lb)
        px.w = hlog2(hexp2(yt) - 1.f);      // log2(2^yt - 1); -inf for yt=0
        sh.x4p[xidx(e)] = px;
        disc = 1.f / hlog2((float)e + 2.f);
        const int c4 = sh.hist[4];
        const int c3 = c4 + sh.hist[3];
        const int c2 = c3 + sh.hist[2];
        const int c1 = c2 + sh.hist[1];
        const float gp = (e < c4) ? 15.f : (e < c3) ? 7.f : (e < c2) ? 3.f :
                         (e < c1) ? 1.f : 0.f;
        idcg_term = gp * disc;
    }
    __syncthreads();

    // persistent col-phase registers for column e
    const float4 pc = sh.x4p[xidx(e)];
    const float cx = pc.x, clx = pc.y;
    const float x8f = hexp2(8.f * clx);     // |8*lx| <= ~104, no overflow
    const unsigned b8 = __float_as_uint(x8f);
    const int ex8 = (int)(b8 >> 23) - 127;
    const float x8m = __uint_as_float((b8 & 0x007FFFFFu) | 0x3F800000u);

    // ---- initial centering grid from m_i = max_j(ld_j + i*lx_j) ----
    {
        float mp = -3.4e38f;
        const float ef = (float)e;
#pragma unroll 8
        for (int j = hh * (NN / 2); j < (hh + 1) * (NN / 2); ++j) {
            float4 p = sh.x4p[xidx(j)];
            mp = fmaxf(mp, fmaf(ef, p.y, p.z));
        }
        sh.red[t] = mp;
        __syncthreads();
        if (hh == 0 && (e & 3) == 0)
            sh.cint[e >> 2] = (int)rintf(fmaxf(sh.red[t], sh.red[t + NN]));
        __syncthreads();
    }

    float dummy;
    row_phase<true, false>(sh, t, 0.f, &dummy);          // softmax (first row norm)
    for (int it = 0; it < SINK_ITERS; ++it) {
        col_phase(sh, t, cx, x8m, ex8, clx);             // col normalize
        row_phase<true, false>(sh, t, 0.f, &dummy);      // row normalize
    }
    float term = 0.f;
    row_phase<false, true>(sh, t, disc, &term);          // epilogue: gains-weighted row sums

    // ---- final reductions ----
    sh.red[t] = term;
    __syncthreads();
    for (int st = NT / 2; st > 0; st >>= 1) {
        if (t < st) sh.red[t] += sh.red[t + st];
        __syncthreads();
    }
    if (t == 0) sh.resA = sh.red[0];
    __syncthreads();
    sh.red[t] = idcg_term;
    __syncthreads();
    for (int st = NT / 2; st > 0; st >>= 1) {
        if (t < st) sh.red[t] += sh.red[t + st];
        __syncthreads();
    }
    if (t == 0) {
        const float idcg = sh.red[0];
        const bool ok = (idcg != 0.f);
        ws[2 * b + 0] = ok ? sh.resA / (idcg + EPSF) : 0.f;
        ws[2 * b + 1] = ok ? 1.f : 0.f;
    }
}

__global__ __launch_bounds__(NB) void ndcg_finalize_kernel(const float* __restrict__ ws,
                                                           float* __restrict__ out) {
    const int t = threadIdx.x;
    __shared__ float rn[NB];
    __shared__ float rc[NB];
    rn[t] = ws[2 * t + 0];
    rc[t] = ws[2 * t + 1];
    __syncthreads();
    for (int st = NB / 2; st > 0; st >>= 1) {
        if (t < st) { rn[t] += rn[t + st]; rc[t] += rc[t + st]; }
        __syncthreads();
    }
    if (t == 0) out[0] = -rn[0] / rc[0];
}

extern "C" void kernel_launch(void* const* d_in, const int* in_sizes, int n_in,
                              void* d_out, int out_size, void* d_ws, size_t ws_size,
                              hipStream_t stream) {
    const float* y_pred = (const float*)d_in[0];
    const float* y_true = (const float*)d_in[1];
    float* out = (float*)d_out;
    float* ws  = (float*)d_ws;

    ndcg_main_kernel<<<NB, NT, 0, stream>>>(y_pred, y_true, ws);
    ndcg_finalize_kernel<<<1, NB, 0, stream>>>(ws, out);
}

// Round 6
// 438.842 us; speedup vs baseline: 29.6761x; 1.1108x over previous
//
#include <hip/hip_runtime.h>
#include <math.h>

#define NB 256
#define NN 512
#define NT 1024
#define SINK_ITERS 50
#define EPSF 1e-10f
#define LOG2E 1.4426950408889634f
#define RPAD 516

typedef float v2f __attribute__((ext_vector_type(2)));

__device__ __forceinline__ float hexp2(float x) { return __builtin_amdgcn_exp2f(x); }
__device__ __forceinline__ float hlog2(float x) { return __builtin_amdgcn_logf(x); }

__device__ __forceinline__ v2f pk_fma(v2f a, v2f b, v2f c) {
    v2f d; asm("v_pk_fma_f32 %0, %1, %2, %3" : "=v"(d) : "v"(a), "v"(b), "v"(c)); return d;
}
__device__ __forceinline__ v2f pk_mul(v2f a, v2f b) {
    v2f d; asm("v_pk_mul_f32 %0, %1, %2" : "=v"(d) : "v"(a), "v"(b)); return d;
}
__device__ __forceinline__ v2f pk_add(v2f a, v2f b) {
    v2f d; asm("v_pk_add_f32 %0, %1, %2" : "=v"(d) : "v"(a), "v"(b)); return d;
}
__device__ __forceinline__ float frexp_mant(float x) {
    float r; asm("v_frexp_mant_f32 %0, %1" : "=v"(r) : "v"(x)); return r;
}
__device__ __forceinline__ int frexp_exp(float x) {
    int r; asm("v_frexp_exp_i32_f32 %0, %1" : "=v"(r) : "v"(x)); return r;
}

// padded SoA indexing: element j -> word W1(j); pair c -> v2f index P2(c)
__device__ __forceinline__ int W1(int j) { return j + ((j >> 4) << 1); }
__device__ __forceinline__ int P2(int c) { return c + (c >> 3); }

struct Shm {
    __align__(16) float red2d[32][RPAD];   // 66 KB cross-tile partials
    __align__(16) v2f   xx[288];           // x_j pairs (padded)
    __align__(16) v2f   ll[288];           // lx_j pairs
    __align__(16) v2f   bb[288];           // lb_j pairs
    __align__(16) v2f   gg[288];           // lgain_j pairs
    __align__(16) float laS[NN];           // row log-scales la_i
    __align__(16) float wD[8 * 66];        // Horner coeffs deinterleaved [k][chunk]
    __align__(16) float red[NT];
    __align__(16) float sS[NN];
    int   cint[128];                       // 4-row-group centering exponents
    int   ccint[64];                       // per-8-coef-chunk centering
    int   hist[5];
    float resA;
};

// Invariant: M_ij = exp2(la_i + lb_j + i*lx_j). Row phase recomputes la (or epilogue terms).
template<bool UPDLA, bool ADDG>
__device__ __forceinline__ void row_phase(Shm& sh, int t, float disc, float* termOut) {
    const int cg = t & 31;                 // column group: j in [16cg, 16cg+16)
    const int rc = t >> 5;                 // row chunk:   i in [16rc, 16rc+16)
    const int r0 = rc * 4;
    const float i0f = (float)(rc * 16);

    const int c0 = sh.cint[r0], c1 = sh.cint[r0 + 1],
              c2 = sh.cint[r0 + 2], c3 = sh.cint[r0 + 3];

    v2f q[8], xv[8];
    {
        const v2f bi = {i0f, i0f};
        const v2f bc = {-(float)c0, -(float)c0};
#pragma unroll
        for (int k = 0; k < 8; ++k) {
            const int p = P2(8 * cg + k);
            v2f lq = pk_fma(bi, sh.ll[p], sh.bb[p]);
            lq = pk_add(lq, bc);
            if (ADDG) lq = pk_add(lq, sh.gg[p]);
            v2f qq;
            qq.x = hexp2(fminf(lq.x, 126.f));
            qq.y = hexp2(fminf(lq.y, 126.f));
            q[k] = qq;
            xv[k] = sh.xx[p];
        }
    }

    float4 sbuf;
#pragma unroll
    for (int r = 0; r < 16; ++r) {
        v2f t0 = pk_add(q[0], q[1]);
        v2f t1 = pk_add(q[2], q[3]);
        v2f t2 = pk_add(q[4], q[5]);
        v2f t3 = pk_add(q[6], q[7]);
        t0 = pk_add(t0, t1);
        t2 = pk_add(t2, t3);
        t0 = pk_add(t0, t2);
        ((float*)&sbuf)[r & 3] = t0.x + t0.y;
        if ((r & 3) == 3)
            *(float4*)&sh.red2d[cg][rc * 16 + (r & ~3)] = sbuf;
        if (r < 15) {
#pragma unroll
            for (int k = 0; k < 8; ++k) q[k] = pk_mul(q[k], xv[k]);
            if (r == 3 || r == 7 || r == 11) {
                int d = (r == 3) ? (c0 - c1) : (r == 7) ? (c1 - c2) : (c2 - c3);
                d = d < -126 ? -126 : (d > 127 ? 127 : d);
                const float f = __int_as_float((d + 127) << 23);
                const v2f f2 = {f, f};
#pragma unroll
                for (int k = 0; k < 8; ++k) q[k] = pk_mul(q[k], f2);
            }
        }
    }
    __syncthreads();
    {   // split 32-deep reduction across all 1024 threads
        const int e = t & (NN - 1);
        const int hh = t >> 9;
        float T = 0.f;
#pragma unroll
        for (int k = 16 * hh; k < 16 * hh + 16; ++k) T += sh.red2d[k][e];
        sh.red[t] = T;
    }
    __syncthreads();
    if (t < NN) {
        const float T = sh.red[t] + sh.red[t + NN];
        const float lT = hlog2(T) + (float)sh.cint[t >> 2];
        if (UPDLA) {
            sh.laS[t] = -lT;
            if ((t & 3) == 0) sh.cint[t >> 2] = (int)rintf(lT);  // same-wave lockstep
        } else {
            *termOut = hexp2(sh.laS[t] + lT) * disc;
        }
    }
    __syncthreads();
}

// Col phase: P(x_j) = sum_i exp2(la_i) x_j^i, chunked Horner (8-deep) + frexp-based
// extended-exponent combine. lb_j <- -log2(colsum) (self-normalizing).
__device__ __forceinline__ void col_phase(Shm& sh, int t, float cx, float x8m, int ex8, float clx) {
    const int jc = t & (NN - 1);
    const int hc = t >> 9;

    if (t < NN) {                          // chunk-centered coefficients, deinterleaved
        const int ch = t >> 3, b8 = ch << 3;
        float mx = sh.laS[b8];
#pragma unroll
        for (int k = 1; k < 8; ++k) mx = fmaxf(mx, sh.laS[b8 + k]);
        const int cci = (int)rintf(mx);
        sh.wD[(t & 7) * 66 + ch] = hexp2(sh.laS[t] - (float)cci);
        if ((t & 7) == 0) sh.ccint[ch] = cci;
    }
    __syncthreads();

    float A = 0.f;
    int   E = -(1 << 30);
    const v2f cx2 = {cx, cx};
    const int chb = hc * 32;
#pragma unroll
    for (int g = 7; g >= 0; --g) {         // 8 groups x 4 chunks, descending
        const int c0 = chb + 4 * g;
        v2f wa[8], wb[8];
#pragma unroll
        for (int k = 0; k < 8; ++k) {
            const float4 w4 = *(const float4*)&sh.wD[k * 66 + c0];  // broadcast read
            v2f a; a.x = w4.x; a.y = w4.y; wa[k] = a;
            v2f b; b.x = w4.z; b.y = w4.w; wb[k] = b;
        }
        v2f ha = wa[7], hb = wb[7];
#pragma unroll
        for (int k = 6; k >= 0; --k) {
            ha = pk_fma(ha, cx2, wa[k]);
            hb = pk_fma(hb, cx2, wb[k]);
        }
        // combine descending: chunk c0+3 (hb.y), c0+2 (hb.x), c0+1 (ha.y), c0 (ha.x)
        const float hs[4] = {hb.y, hb.x, ha.y, ha.x};
#pragma unroll
        for (int u = 0; u < 4; ++u) {
            const int cc = sh.ccint[c0 + 3 - u];
            const int eP = E + ex8;
            const int d = cc - eP;
            const int dA = (-d < 0) ? -d : 0;
            const int dH = (d < 0) ? d : 0;
            const float An = ldexpf(A * x8m, dA) + ldexpf(hs[u], dH);
            const int base = (eP > cc) ? eP : cc;
            A = frexp_mant(An);
            E = base + frexp_exp(An);
        }
    }
    float lV = hlog2(A) + (float)E;        // A==0 -> -inf (first-iter only)
    if (hc) lV = fmaf(256.f, clx, lV);
    sh.red[jc + NN * hc] = lV;
    __syncthreads();
    if (t < NN) {
        const float a = sh.red[t], b2 = sh.red[t + NN];
        const float L = fmaxf(a, b2), S = fminf(a, b2);
        const float lb = (L < -1e30f) ? 0.f : -(L + hlog2(1.f + hexp2(S - L)));
        ((float*)sh.bb)[W1(t)] = lb;
    }
    __syncthreads();
}

__global__ __launch_bounds__(NT) void ndcg_main_kernel(const float* __restrict__ y_pred,
                                                       const float* __restrict__ y_true,
                                                       float* __restrict__ ws) {
    __shared__ Shm sh;
    const int b = blockIdx.x;
    const int t = threadIdx.x;
    const int e = t & (NN - 1);
    const int hh = t >> 9;

    // ---- pass 0: loads, histogram, R_j, SoA column tables, idcg ----
    float yt = 0.f, s = 0.f, disc = 0.f, idcg_term = 0.f;
    if (t < NN) { s = y_pred[b * NN + t]; yt = y_true[b * NN + t]; sh.sS[t] = s; }
    if (t < 5) sh.hist[t] = 0;
    __syncthreads();
    if (t < NN) {
        int vi = (int)(yt + 0.5f);
        vi = vi < 0 ? 0 : (vi > 4 ? 4 : vi);
        atomicAdd(&sh.hist[vi], 1);
    }
    const float se = sh.sS[e];
    const float4* sS4 = (const float4*)sh.sS;
    float Rp = 0.f;
#pragma unroll 8
    for (int m = hh * (NN / 8); m < (hh + 1) * (NN / 8); ++m) {
        float4 f = sS4[m];
        Rp += fabsf(se - f.x) + fabsf(se - f.y) + fabsf(se - f.z) + fabsf(se - f.w);
    }
    sh.red[t] = Rp;
    __syncthreads();                       // covers hist atomics
    if (hh == 0) {
        const float R = sh.red[t] + sh.red[t + NN];
        const float sL = se * LOG2E;
        const float lx = -2.f * sL;
        const int w = W1(e);
        ((float*)sh.xx)[w] = hexp2(lx);
        ((float*)sh.ll)[w] = lx;
        ((float*)sh.bb)[w] = fmaf(511.f, sL, -R * LOG2E);
        ((float*)sh.gg)[w] = hlog2(hexp2(yt) - 1.f);   // -inf for yt==0 (safe)
        disc = 1.f / hlog2((float)e + 2.f);
        const int c4 = sh.hist[4];
        const int c3 = c4 + sh.hist[3];
        const int c2 = c3 + sh.hist[2];
        const int c1 = c2 + sh.hist[1];
        const float gp = (e < c4) ? 15.f : (e < c3) ? 7.f : (e < c2) ? 3.f :
                         (e < c1) ? 1.f : 0.f;
        idcg_term = gp * disc;
    }
    __syncthreads();

    // persistent col-phase constants for column e
    const float cx  = ((float*)sh.xx)[W1(e)];
    const float clx = ((float*)sh.ll)[W1(e)];
    const float x8f = hexp2(8.f * clx);    // |8*lx| <= ~110, no overflow
    const unsigned b8 = __float_as_uint(x8f);
    const int ex8 = (int)(b8 >> 23) - 127;
    const float x8m = __uint_as_float((b8 & 0x007FFFFFu) | 0x3F800000u);

    // ---- initial centering grid from m_i = max_j(ld_j + i*lx_j) ----
    {
        float mp = -3.4e38f;
        const v2f e2 = {(float)e, (float)e};
#pragma unroll 8
        for (int p = hh * 128; p < hh * 128 + 128; ++p) {
            const int pi = P2(p);
            v2f lq = pk_fma(e2, sh.ll[pi], sh.bb[pi]);
            mp = fmaxf(mp, fmaxf(lq.x, lq.y));
        }
        sh.red[t] = mp;
        __syncthreads();
        if (hh == 0 && (e & 3) == 0)
            sh.cint[e >> 2] = (int)rintf(fmaxf(sh.red[t], sh.red[t + NN]));
        __syncthreads();
    }

    float dummy;
    row_phase<true, false>(sh, t, 0.f, &dummy);          // softmax (first row norm)
    for (int it = 0; it < SINK_ITERS; ++it) {
        col_phase(sh, t, cx, x8m, ex8, clx);             // col normalize
        row_phase<true, false>(sh, t, 0.f, &dummy);      // row normalize
    }
    float term = 0.f;
    row_phase<false, true>(sh, t, disc, &term);          // epilogue: gains-weighted row sums

    // ---- final reductions ----
    sh.red[t] = term;
    __syncthreads();
    for (int st = NT / 2; st > 0; st >>= 1) {
        if (t < st) sh.red[t] += sh.red[t + st];
        __syncthreads();
    }
    if (t == 0) sh.resA = sh.red[0];
    __syncthreads();
    sh.red[t] = idcg_term;
    __syncthreads();
    for (int st = NT / 2; st > 0; st >>= 1) {
        if (t < st) sh.red[t] += sh.red[t + st];
        __syncthreads();
    }
    if (t == 0) {
        const float idcg = sh.red[0];
        const bool ok = (idcg != 0.f);
        ws[2 * b + 0] = ok ? sh.resA / (idcg + EPSF) : 0.f;
        ws[2 * b + 1] = ok ? 1.f : 0.f;
    }
}

__global__ __launch_bounds__(NB) void ndcg_finalize_kernel(const float* __restrict__ ws,
                                                           float* __restrict__ out) {
    const int t = threadIdx.x;
    __shared__ float rn[NB];
    __shared__ float rc[NB];
    rn[t] = ws[2 * t + 0];
    rc[t] = ws[2 * t + 1];
    __syncthreads();
    for (int st = NB / 2; st > 0; st >>= 1) {
        if (t < st) { rn[t] += rn[t + st]; rc[t] += rc[t + st]; }
        __syncthreads();
    }
    if (t == 0) out[0] = -rn[0] / rc[0];
}

extern "C" void kernel_launch(void* const* d_in, const int* in_sizes, int n_in,
                              void* d_out, int out_size, void* d_ws, size_t ws_size,
                              hipStream_t stream) {
    const float* y_pred = (const float*)d_in[0];
    const float* y_true = (const float*)d_in[1];
    float* out = (float*)d_out;
    float* ws  = (float*)d_ws;

    ndcg_main_kernel<<<NB, NT, 0, stream>>>(y_pred, y_true, ws);
    ndcg_finalize_kernel<<<1, NB, 0, stream>>>(ws, out);
}

// Round 7
// 421.639 us; speedup vs baseline: 30.8869x; 1.0408x over previous
//
#include <hip/hip_runtime.h>
#include <math.h>

#define NB 256
#define NN 512
#define NT 1024
#define SINK_ITERS 50
#define EPSF 1e-10f
#define LOG2E 1.4426950408889634f
#define RPAD 516

typedef float v2f __attribute__((ext_vector_type(2)));

__device__ __forceinline__ float hexp2(float x) { return __builtin_amdgcn_exp2f(x); }
__device__ __forceinline__ float hlog2(float x) { return __builtin_amdgcn_logf(x); }

__device__ __forceinline__ v2f pk_fma(v2f a, v2f b, v2f c) {
    v2f d; asm("v_pk_fma_f32 %0, %1, %2, %3" : "=v"(d) : "v"(a), "v"(b), "v"(c)); return d;
}
__device__ __forceinline__ v2f pk_mul(v2f a, v2f b) {
    v2f d; asm("v_pk_mul_f32 %0, %1, %2" : "=v"(d) : "v"(a), "v"(b)); return d;
}
__device__ __forceinline__ v2f pk_add(v2f a, v2f b) {
    v2f d; asm("v_pk_add_f32 %0, %1, %2" : "=v"(d) : "v"(a), "v"(b)); return d;
}
__device__ __forceinline__ float frexp_mant(float x) {
    float r; asm("v_frexp_mant_f32 %0, %1" : "=v"(r) : "v"(x)); return r;
}
__device__ __forceinline__ int frexp_exp(float x) {
    int r; asm("v_frexp_exp_i32_f32 %0, %1" : "=v"(r) : "v"(x)); return r;
}

// padded SoA indexing: element j -> word W1(j); pair c -> v2f index P2(c)
__device__ __forceinline__ int W1(int j) { return j + ((j >> 4) << 1); }
__device__ __forceinline__ int P2(int c) { return c + (c >> 3); }

struct Shm {
    __align__(16) float red2d[32][RPAD];   // 66 KB cross-tile partials
    __align__(16) v2f   xx[288];           // x_j pairs (padded)
    __align__(16) v2f   ll[288];           // lx_j pairs
    __align__(16) v2f   bb[288];           // lb_j pairs
    __align__(16) v2f   gg[288];           // lgain_j pairs
    __align__(16) float laS[NN];           // row log-scales la_i
    __align__(16) float wD[8 * 66];        // Horner coeffs deinterleaved [k][chunk]
    __align__(16) float red[NT];
    __align__(16) float sS[NN];
    __align__(16) int   cint[128];         // 4-row-group centering exponents (wave-private)
    __align__(16) int   ccint[64];         // per-8-coef-chunk centering
    int   hist[5];
    float resA;
};

// Invariant: M_ij = exp2(la_i + lb_j + i*lx_j). Row main: write per-(colgroup,row) partials.
template<bool ADDG>
__device__ __forceinline__ void row_main(Shm& sh, int t) {
    const int cg = t & 31;                 // column group: j in [16cg, 16cg+16)
    const int rc = t >> 5;                 // row chunk:   i in [16rc, 16rc+16)
    const float i0f = (float)(rc * 16);
    const int4 ci = *(const int4*)&sh.cint[rc * 4];
    const int c0 = ci.x, c1 = ci.y, c2 = ci.z, c3 = ci.w;

    v2f q[8], xv[8];
    {
        const v2f bi = {i0f, i0f};
        const v2f bc = {-(float)c0, -(float)c0};
#pragma unroll
        for (int k = 0; k < 8; ++k) {
            const int p = P2(8 * cg + k);
            v2f lq = pk_fma(bi, sh.ll[p], sh.bb[p]);
            lq = pk_add(lq, bc);
            if (ADDG) lq = pk_add(lq, sh.gg[p]);
            v2f qq;
            qq.x = hexp2(fminf(lq.x, 126.f));
            qq.y = hexp2(fminf(lq.y, 126.f));
            q[k] = qq;
            xv[k] = sh.xx[p];
        }
    }
    float4 sbuf;
#pragma unroll
    for (int r = 0; r < 16; ++r) {
        v2f t0 = pk_add(q[0], q[1]);
        v2f t1 = pk_add(q[2], q[3]);
        v2f t2 = pk_add(q[4], q[5]);
        v2f t3 = pk_add(q[6], q[7]);
        t0 = pk_add(t0, t1);
        t2 = pk_add(t2, t3);
        t0 = pk_add(t0, t2);
        ((float*)&sbuf)[r & 3] = t0.x + t0.y;
        if ((r & 3) == 3)
            *(float4*)&sh.red2d[cg][rc * 16 + (r & ~3)] = sbuf;
        if (r < 15) {
#pragma unroll
            for (int k = 0; k < 8; ++k) q[k] = pk_mul(q[k], xv[k]);
            if (r == 3 || r == 7 || r == 11) {
                int d = (r == 3) ? (c0 - c1) : (r == 7) ? (c1 - c2) : (c2 - c3);
                d = d < -126 ? -126 : (d > 127 ? 127 : d);
                const float f = __int_as_float((d + 127) << 23);
                const v2f f2 = {f, f};
#pragma unroll
                for (int k = 0; k < 8; ++k) q[k] = pk_mul(q[k], f2);
            }
        }
    }
}

// Phase X (barrier-free internals): reduce partials -> T_e, la_e, cint update,
// per-8 chunk centering via shfl, Horner coefficient write. Wave-local hand-offs only.
__device__ __forceinline__ void phaseX(Shm& sh, int t) {
    const int l  = t & 63;
    const int eW = ((t >> 6) << 5) + (l & 31);
    const int hW = l >> 5;

    float S = 0.f;
#pragma unroll
    for (int k = 16 * hW; k < 16 * hW + 16; ++k) S += sh.red2d[k][eW];
    S += __shfl_xor(S, 32);                // full T_e (both halves hold it)

    const float lT = hlog2(S) + (float)sh.cint[eW >> 2];   // read-before-write, same wave
    const float la = -lT;

    float mx = la;                         // max over the 8-row chunk (lanes grouped by 8)
    mx = fmaxf(mx, __shfl_xor(mx, 1));
    mx = fmaxf(mx, __shfl_xor(mx, 2));
    mx = fmaxf(mx, __shfl_xor(mx, 4));
    const int cci = (int)rintf(mx);

    if (hW == 0) {
        sh.laS[eW] = la;
        sh.wD[(eW & 7) * 66 + (eW >> 3)] = hexp2(la - (float)cci);
        if ((eW & 7) == 0) sh.ccint[eW >> 3] = cci;
        if ((eW & 3) == 0) sh.cint[eW >> 2] = (int)rintf(lT);
    }
}

// Col main: P(x_j) = sum_i exp2(la_i) x_j^i, chunked Horner + extended-exponent combine;
// two halves combined in-wave via shfl; lb_j written by low-half lanes.
__device__ __forceinline__ void col_main(Shm& sh, int t, int eW, int hW,
                                         float cx, float x8m, int ex8, float clx) {
    const int chb = hW * 32;
    int4 cc8[8];
#pragma unroll
    for (int qq = 0; qq < 8; ++qq) cc8[qq] = *(const int4*)&sh.ccint[chb + 4 * qq];

    float A = 0.f;
    int   E = -(1 << 30);
    const v2f cx2 = {cx, cx};
#pragma unroll
    for (int g = 7; g >= 0; --g) {         // 8 groups x 4 chunks, descending
        const int c0 = chb + 4 * g;
        v2f wa[8], wb[8];
#pragma unroll
        for (int k = 0; k < 8; ++k) {
            const float4 w4 = *(const float4*)&sh.wD[k * 66 + c0];  // broadcast read
            v2f a; a.x = w4.x; a.y = w4.y; wa[k] = a;
            v2f b2; b2.x = w4.z; b2.y = w4.w; wb[k] = b2;
        }
        v2f ha = wa[7], hb = wb[7];
#pragma unroll
        for (int k = 6; k >= 0; --k) {
            ha = pk_fma(ha, cx2, wa[k]);
            hb = pk_fma(hb, cx2, wb[k]);
        }
        const float hs[4] = {hb.y, hb.x, ha.y, ha.x};
#pragma unroll
        for (int u = 0; u < 4; ++u) {
            const int cidx = 4 * g + 3 - u;
            const int cc = ((const int*)cc8)[cidx];
            const int eP = E + ex8;
            const int d = cc - eP;
            const int dA = (-d < 0) ? -d : 0;
            const int dH = (d < 0) ? d : 0;
            const float An = ldexpf(A * x8m, dA) + ldexpf(hs[u], dH);
            const int base = (eP > cc) ? eP : cc;
            A = frexp_mant(An);
            E = base + frexp_exp(An);
        }
    }
    float lV = hlog2(A) + (float)E;        // A==0 -> -inf (benign)
    if (hW) lV = fmaf(256.f, clx, lV);

    const float oV = __shfl_xor(lV, 32);   // other half, same column
    const float L = fmaxf(lV, oV), Sm = fminf(lV, oV);
    const float lb = (L < -1e30f) ? 0.f : -(L + hlog2(1.f + hexp2(Sm - L)));
    if (hW == 0) ((float*)sh.bb)[W1(eW)] = lb;
}

__global__ __launch_bounds__(NT) void ndcg_main_kernel(const float* __restrict__ y_pred,
                                                       const float* __restrict__ y_true,
                                                       float* __restrict__ ws) {
    __shared__ Shm sh;
    const int b = blockIdx.x;
    const int t = threadIdx.x;
    const int e = t & (NN - 1);
    const int hh = t >> 9;
    const int l  = t & 63;
    const int eW = ((t >> 6) << 5) + (l & 31);   // wave-local column/row index
    const int hW = l >> 5;

    // ---- pass 0: loads, histogram, R_j, SoA column tables, idcg ----
    float yt = 0.f, s = 0.f, idcg_term = 0.f;
    if (t < NN) { s = y_pred[b * NN + t]; yt = y_true[b * NN + t]; sh.sS[t] = s; }
    if (t < 5) sh.hist[t] = 0;
    __syncthreads();
    if (t < NN) {
        int vi = (int)(yt + 0.5f);
        vi = vi < 0 ? 0 : (vi > 4 ? 4 : vi);
        atomicAdd(&sh.hist[vi], 1);
    }
    const float se = sh.sS[e];
    const float4* sS4 = (const float4*)sh.sS;
    float Rp = 0.f;
#pragma unroll 8
    for (int m = hh * (NN / 8); m < (hh + 1) * (NN / 8); ++m) {
        float4 f = sS4[m];
        Rp += fabsf(se - f.x) + fabsf(se - f.y) + fabsf(se - f.z) + fabsf(se - f.w);
    }
    sh.red[t] = Rp;
    __syncthreads();                       // covers hist atomics
    if (hh == 0) {
        const float R = sh.red[t] + sh.red[t + NN];
        const float sL = se * LOG2E;
        const float lx = -2.f * sL;
        const int w = W1(e);
        ((float*)sh.xx)[w] = hexp2(lx);
        ((float*)sh.ll)[w] = lx;
        ((float*)sh.bb)[w] = fmaf(511.f, sL, -R * LOG2E);
        ((float*)sh.gg)[w] = hlog2(hexp2(yt) - 1.f);   // -inf for yt==0 (safe)
        const float dsc = 1.f / hlog2((float)e + 2.f);
        const int c4 = sh.hist[4];
        const int c3 = c4 + sh.hist[3];
        const int c2 = c3 + sh.hist[2];
        const int c1 = c2 + sh.hist[1];
        const float gp = (e < c4) ? 15.f : (e < c3) ? 7.f : (e < c2) ? 3.f :
                         (e < c1) ? 1.f : 0.f;
        idcg_term = gp * dsc;
    }
    __syncthreads();

    // persistent col-phase constants for column eW
    const float cx  = ((float*)sh.xx)[W1(eW)];
    const float clx = ((float*)sh.ll)[W1(eW)];
    const float x8f = hexp2(8.f * clx);    // |8*lx| <= ~110, no overflow
    const unsigned b8 = __float_as_uint(x8f);
    const int ex8 = (int)(b8 >> 23) - 127;
    const float x8m = __uint_as_float((b8 & 0x007FFFFFu) | 0x3F800000u);

    // ---- initial centering grid from m_i = max_j(ld_j + i*lx_j) ----
    {
        float mp = -3.4e38f;
        const v2f e2 = {(float)e, (float)e};
#pragma unroll 8
        for (int p = hh * 128; p < hh * 128 + 128; ++p) {
            const int pi = P2(p);
            v2f lq = pk_fma(e2, sh.ll[pi], sh.bb[pi]);
            mp = fmaxf(mp, fmaxf(lq.x, lq.y));
        }
        sh.red[t] = mp;
        __syncthreads();
        if (hh == 0 && (e & 3) == 0)
            sh.cint[e >> 2] = (int)rintf(fmaxf(sh.red[t], sh.red[t + NN]));
        __syncthreads();
    }

    // ---- softmax (first row normalization) ----
    row_main<false>(sh, t);
    __syncthreads();
    phaseX(sh, t);
    __syncthreads();

    // ---- Sinkhorn: 50 x { col-normalize, row-normalize }, 3 barriers/iter ----
    for (int it = 0; it < SINK_ITERS; ++it) {
        col_main(sh, t, eW, hW, cx, x8m, ex8, clx);
        __syncthreads();
        row_main<false>(sh, t);
        __syncthreads();
        phaseX(sh, t);
        __syncthreads();
    }

    // ---- epilogue: gains-weighted row sums ----
    row_main<true>(sh, t);
    __syncthreads();
    float term = 0.f;
    {
        float S = 0.f;
#pragma unroll
        for (int k = 16 * hW; k < 16 * hW + 16; ++k) S += sh.red2d[k][eW];
        S += __shfl_xor(S, 32);
        const float lT = hlog2(S) + (float)sh.cint[eW >> 2];
        if (hW == 0)
            term = hexp2(sh.laS[eW] + lT) / hlog2((float)eW + 2.f);
    }
    sh.red[t] = term;
    __syncthreads();
    for (int st = NT / 2; st > 0; st >>= 1) {
        if (t < st) sh.red[t] += sh.red[t + st];
        __syncthreads();
    }
    if (t == 0) sh.resA = sh.red[0];
    __syncthreads();
    sh.red[t] = idcg_term;
    __syncthreads();
    for (int st = NT / 2; st > 0; st >>= 1) {
        if (t < st) sh.red[t] += sh.red[t + st];
        __syncthreads();
    }
    if (t == 0) {
        const float idcg = sh.red[0];
        const bool ok = (idcg != 0.f);
        ws[2 * b + 0] = ok ? sh.resA / (idcg + EPSF) : 0.f;
        ws[2 * b + 1] = ok ? 1.f : 0.f;
    }
}

__global__ __launch_bounds__(NB) void ndcg_finalize_kernel(const float* __restrict__ ws,
                                                           float* __restrict__ out) {
    const int t = threadIdx.x;
    __shared__ float rn[NB];
    __shared__ float rc[NB];
    rn[t] = ws[2 * t + 0];
    rc[t] = ws[2 * t + 1];
    __syncthreads();
    for (int st = NB / 2; st > 0; st >>= 1) {
        if (t < st) { rn[t] += rn[t + st]; rc[t] += rc[t + st]; }
        __syncthreads();
    }
    if (t == 0) out[0] = -rn[0] / rc[0];
}

extern "C" void kernel_launch(void* const* d_in, const int* in_sizes, int n_in,
                              void* d_out, int out_size, void* d_ws, size_t ws_size,
                              hipStream_t stream) {
    const float* y_pred = (const float*)d_in[0];
    const float* y_true = (const float*)d_in[1];
    float* out = (float*)d_out;
    float* ws  = (float*)d_ws;

    ndcg_main_kernel<<<NB, NT, 0, stream>>>(y_pred, y_true, ws);
    ndcg_finalize_kernel<<<1, NB, 0, stream>>>(ws, out);
}

// Round 8
// 387.135 us; speedup vs baseline: 33.6397x; 1.0891x over previous
//
#include <hip/hip_runtime.h>
#include <math.h>

#define NB 256
#define NN 512
#define NT 1024
#define SINK_ITERS 50
#define EPSF 1e-10f
#define LOG2E 1.4426950408889634f
#define RPAD 516

typedef float v2f __attribute__((ext_vector_type(2)));

__device__ __forceinline__ float hexp2(float x) { return __builtin_amdgcn_exp2f(x); }
__device__ __forceinline__ float hlog2(float x) { return __builtin_amdgcn_logf(x); }

__device__ __forceinline__ v2f pk_fma(v2f a, v2f b, v2f c) {
    v2f d; asm("v_pk_fma_f32 %0, %1, %2, %3" : "=v"(d) : "v"(a), "v"(b), "v"(c)); return d;
}
__device__ __forceinline__ v2f pk_mul(v2f a, v2f b) {
    v2f d; asm("v_pk_mul_f32 %0, %1, %2" : "=v"(d) : "v"(a), "v"(b)); return d;
}
__device__ __forceinline__ v2f pk_add(v2f a, v2f b) {
    v2f d; asm("v_pk_add_f32 %0, %1, %2" : "=v"(d) : "v"(a), "v"(b)); return d;
}

// padded SoA indexing: element j -> word W1(j); pair c -> v2f index P2(c)
__device__ __forceinline__ int W1(int j) { return j + ((j >> 4) << 1); }
__device__ __forceinline__ int P2(int c) { return c + (c >> 3); }

struct Shm {
    __align__(16) float red2d[32][RPAD];   // 66 KB cross-tile partials
    __align__(16) v2f   xx[288];           // x_j pairs (padded)
    __align__(16) v2f   ll[288];           // lx_j pairs
    __align__(16) v2f   bb[288];           // lb_j pairs
    __align__(16) v2f   gg[288];           // lgain_j pairs
    __align__(16) float laS[NN];           // row log-scales la_i
    __align__(16) float wD[8 * 66];        // Horner coeffs deinterleaved [k][chunk]
    __align__(16) float red[NT];
    __align__(16) float sS[NN];
    __align__(16) int   cint[128];         // 4-row-group centering exponents (wave-private)
    __align__(16) int   ccint[64];         // per-8-coef-chunk centering
    int   hist[5];
    float resA;
};

// Invariant: M_ij = exp2(la_i + lb_j + i*lx_j). Row main: write per-(colgroup,row) partials.
template<bool ADDG>
__device__ __forceinline__ void row_main(Shm& sh, int t) {
    const int cg = t & 31;                 // column group: j in [16cg, 16cg+16)
    const int rc = t >> 5;                 // row chunk:   i in [16rc, 16rc+16)
    const float i0f = (float)(rc * 16);
    const int4 ci = *(const int4*)&sh.cint[rc * 4];
    const int c0 = ci.x, c1 = ci.y, c2 = ci.z, c3 = ci.w;

    v2f q[8], xv[8];
    {
        const v2f bi = {i0f, i0f};
        const v2f bc = {-(float)c0, -(float)c0};
#pragma unroll
        for (int k = 0; k < 8; ++k) {
            const int p = P2(8 * cg + k);
            v2f lq = pk_fma(bi, sh.ll[p], sh.bb[p]);
            lq = pk_add(lq, bc);
            if (ADDG) lq = pk_add(lq, sh.gg[p]);
            v2f qq;
            qq.x = hexp2(fminf(lq.x, 126.f));
            qq.y = hexp2(fminf(lq.y, 126.f));
            q[k] = qq;
            xv[k] = sh.xx[p];
        }
    }
    float4 sbuf;
#pragma unroll
    for (int r = 0; r < 16; ++r) {
        v2f t0 = pk_add(q[0], q[1]);
        v2f t1 = pk_add(q[2], q[3]);
        v2f t2 = pk_add(q[4], q[5]);
        v2f t3 = pk_add(q[6], q[7]);
        t0 = pk_add(t0, t1);
        t2 = pk_add(t2, t3);
        t0 = pk_add(t0, t2);
        ((float*)&sbuf)[r & 3] = t0.x + t0.y;
        if ((r & 3) == 3)
            *(float4*)&sh.red2d[cg][rc * 16 + (r & ~3)] = sbuf;
        if (r < 15) {
#pragma unroll
            for (int k = 0; k < 8; ++k) q[k] = pk_mul(q[k], xv[k]);
            if (r == 3 || r == 7 || r == 11) {
                int d = (r == 3) ? (c0 - c1) : (r == 7) ? (c1 - c2) : (c2 - c3);
                d = d < -126 ? -126 : (d > 127 ? 127 : d);
                const float f = __int_as_float((d + 127) << 23);
                const v2f f2 = {f, f};
#pragma unroll
                for (int k = 0; k < 8; ++k) q[k] = pk_mul(q[k], f2);
            }
        }
    }
}

// Phase X (barrier-free internals): reduce partials -> T_e, la_e, cint update,
// per-8 chunk centering via shfl, Horner coefficient write. Wave-local hand-offs only.
__device__ __forceinline__ void phaseX(Shm& sh, int t) {
    const int l  = t & 63;
    const int eW = ((t >> 6) << 5) + (l & 31);
    const int hW = l >> 5;

    float S = 0.f;
#pragma unroll
    for (int k = 16 * hW; k < 16 * hW + 16; ++k) S += sh.red2d[k][eW];
    S += __shfl_xor(S, 32);                // full T_e (both halves hold it)

    const float lT = hlog2(S) + (float)sh.cint[eW >> 2];   // read-before-write, same wave
    const float la = -lT;

    float mx = la;                         // max over the 8-row chunk (lanes grouped by 8)
    mx = fmaxf(mx, __shfl_xor(mx, 1));
    mx = fmaxf(mx, __shfl_xor(mx, 2));
    mx = fmaxf(mx, __shfl_xor(mx, 4));
    const int cci = (int)rintf(mx);

    if (hW == 0) {
        sh.laS[eW] = la;
        sh.wD[(eW & 7) * 66 + (eW >> 3)] = hexp2(la - (float)cci);
        if ((eW & 7) == 0) sh.ccint[eW >> 3] = cci;
        if ((eW & 3) == 0) sh.cint[eW >> 2] = (int)rintf(lT);
    }
}

// Col main: P(x_j) = sum_i exp2(la_i) x_j^i. Chunked Horner (packed) + scale-free
// accumulation: chunk value = H_c * x8m^c * 2^(cc_c + c*ex8); pre-pass finds
// B = max_c (cc_c + c*ex8); terms combined via independent ldexp + packed adds.
__device__ __forceinline__ void col_main(Shm& sh, int t, int eW, int hW,
                                         float cx, float x8m, int ex8, float clx) {
    const int chb = hW * 32;
    const int ex8_2 = ex8 + ex8;
    const int ex8_3 = ex8_2 + ex8;
    const int ex8_4 = ex8_2 + ex8_2;

    // pass 1: B = max_c (cc_c + c*ex8)   (c local to this half)
    int B = -(1 << 30);
    {
        int w0 = 0;
#pragma unroll
        for (int g = 0; g < 8; ++g) {
            const int4 cc = *(const int4*)&sh.ccint[chb + 4 * g];
            const int i0 = cc.x + w0;
            const int i1 = cc.y + w0 + ex8;
            const int i2 = cc.z + w0 + ex8_2;
            const int i3 = cc.w + w0 + ex8_3;
            B = max(B, max(max(i0, i1), max(i2, i3)));
            w0 += ex8_4;
        }
    }

    // pass 2: acc = sum_c H_c * W_c * 2^(i_c - B)
    const float x16m = x8m * x8m;          // in [1,4): plain multiplier for the W walk
    const v2f x16m2 = {x16m, x16m};
    const v2f cx2 = {cx, cx};
    v2f accA = {0.f, 0.f}, accB = {0.f, 0.f};
    v2f Wa = {1.f, x8m};                   // {x8m^(4g), x8m^(4g+1)}
    int gb = -B;                           // running cc-offset: 4g*ex8 - B
#pragma unroll
    for (int g = 0; g < 8; ++g) {
        const int c0 = chb + 4 * g;
        v2f wa[8], wb[8];
#pragma unroll
        for (int k = 0; k < 8; ++k) {
            const float4 w4 = *(const float4*)&sh.wD[k * 66 + c0];  // broadcast read
            v2f a; a.x = w4.x; a.y = w4.y; wa[k] = a;
            v2f b2; b2.x = w4.z; b2.y = w4.w; wb[k] = b2;
        }
        v2f ha = wa[7], hb = wb[7];
#pragma unroll
        for (int k = 6; k >= 0; --k) {
            ha = pk_fma(ha, cx2, wa[k]);
            hb = pk_fma(hb, cx2, wb[k]);
        }
        const int4 cc = *(const int4*)&sh.ccint[c0];
        const v2f Wb = pk_mul(Wa, x16m2);  // {x8m^(4g+2), x8m^(4g+3)}
        const v2f t1 = pk_mul(ha, Wa);
        const v2f t2 = pk_mul(hb, Wb);
        v2f u1, u2;
        u1.x = ldexpf(t1.x, cc.x + gb);
        u1.y = ldexpf(t1.y, cc.y + gb + ex8);
        u2.x = ldexpf(t2.x, cc.z + gb + ex8_2);
        u2.y = ldexpf(t2.y, cc.w + gb + ex8_3);
        accA = pk_add(accA, u1);
        accB = pk_add(accB, u2);
        Wa = pk_mul(Wb, x16m2);
        gb += ex8_4;
    }
    const v2f accT = pk_add(accA, accB);
    const float acc = accT.x + accT.y;

    float lV = hlog2(acc) + (float)B;      // acc > 0 always (B-chunk term >= 2^-90)
    if (hW) lV = fmaf(256.f, clx, lV);

    const float oV = __shfl_xor(lV, 32);   // other half, same column
    const float L = fmaxf(lV, oV), Sm = fminf(lV, oV);
    const float lb = (L < -1e30f) ? 0.f : -(L + hlog2(1.f + hexp2(Sm - L)));
    if (hW == 0) ((float*)sh.bb)[W1(eW)] = lb;
}

__global__ __launch_bounds__(NT) void ndcg_main_kernel(const float* __restrict__ y_pred,
                                                       const float* __restrict__ y_true,
                                                       float* __restrict__ ws) {
    __shared__ Shm sh;
    const int b = blockIdx.x;
    const int t = threadIdx.x;
    const int e = t & (NN - 1);
    const int hh = t >> 9;
    const int l  = t & 63;
    const int eW = ((t >> 6) << 5) + (l & 31);   // wave-local column/row index
    const int hW = l >> 5;

    // ---- pass 0: loads, histogram, R_j, SoA column tables, idcg ----
    float yt = 0.f, s = 0.f, idcg_term = 0.f;
    if (t < NN) { s = y_pred[b * NN + t]; yt = y_true[b * NN + t]; sh.sS[t] = s; }
    if (t < 5) sh.hist[t] = 0;
    __syncthreads();
    if (t < NN) {
        int vi = (int)(yt + 0.5f);
        vi = vi < 0 ? 0 : (vi > 4 ? 4 : vi);
        atomicAdd(&sh.hist[vi], 1);
    }
    const float se = sh.sS[e];
    const float4* sS4 = (const float4*)sh.sS;
    float Rp = 0.f;
#pragma unroll 8
    for (int m = hh * (NN / 8); m < (hh + 1) * (NN / 8); ++m) {
        float4 f = sS4[m];
        Rp += fabsf(se - f.x) + fabsf(se - f.y) + fabsf(se - f.z) + fabsf(se - f.w);
    }
    sh.red[t] = Rp;
    __syncthreads();                       // covers hist atomics
    if (hh == 0) {
        const float R = sh.red[t] + sh.red[t + NN];
        const float sL = se * LOG2E;
        const float lx = -2.f * sL;
        const int w = W1(e);
        ((float*)sh.xx)[w] = hexp2(lx);
        ((float*)sh.ll)[w] = lx;
        ((float*)sh.bb)[w] = fmaf(511.f, sL, -R * LOG2E);
        ((float*)sh.gg)[w] = hlog2(hexp2(yt) - 1.f);   // -inf for yt==0 (safe)
        const float dsc = 1.f / hlog2((float)e + 2.f);
        const int c4 = sh.hist[4];
        const int c3 = c4 + sh.hist[3];
        const int c2 = c3 + sh.hist[2];
        const int c1 = c2 + sh.hist[1];
        const float gp = (e < c4) ? 15.f : (e < c3) ? 7.f : (e < c2) ? 3.f :
                         (e < c1) ? 1.f : 0.f;
        idcg_term = gp * dsc;
    }
    __syncthreads();

    // persistent col-phase constants for column eW
    const float cx  = ((float*)sh.xx)[W1(eW)];
    const float clx = ((float*)sh.ll)[W1(eW)];
    const float x8f = hexp2(8.f * clx);    // |8*lx| <= ~110, no overflow
    const unsigned b8 = __float_as_uint(x8f);
    const int ex8 = (int)(b8 >> 23) - 127;
    const float x8m = __uint_as_float((b8 & 0x007FFFFFu) | 0x3F800000u);

    // ---- initial centering grid from m_i = max_j(ld_j + i*lx_j) ----
    {
        float mp = -3.4e38f;
        const v2f e2 = {(float)e, (float)e};
#pragma unroll 8
        for (int p = hh * 128; p < hh * 128 + 128; ++p) {
            const int pi = P2(p);
            v2f lq = pk_fma(e2, sh.ll[pi], sh.bb[pi]);
            mp = fmaxf(mp, fmaxf(lq.x, lq.y));
        }
        sh.red[t] = mp;
        __syncthreads();
        if (hh == 0 && (e & 3) == 0)
            sh.cint[e >> 2] = (int)rintf(fmaxf(sh.red[t], sh.red[t + NN]));
        __syncthreads();
    }

    // ---- softmax (first row normalization) ----
    row_main<false>(sh, t);
    __syncthreads();
    phaseX(sh, t);
    __syncthreads();

    // ---- Sinkhorn: 50 x { col-normalize, row-normalize }, 3 barriers/iter ----
    for (int it = 0; it < SINK_ITERS; ++it) {
        col_main(sh, t, eW, hW, cx, x8m, ex8, clx);
        __syncthreads();
        row_main<false>(sh, t);
        __syncthreads();
        phaseX(sh, t);
        __syncthreads();
    }

    // ---- epilogue: gains-weighted row sums ----
    row_main<true>(sh, t);
    __syncthreads();
    float term = 0.f;
    {
        float S = 0.f;
#pragma unroll
        for (int k = 16 * hW; k < 16 * hW + 16; ++k) S += sh.red2d[k][eW];
        S += __shfl_xor(S, 32);
        const float lT = hlog2(S) + (float)sh.cint[eW >> 2];
        if (hW == 0)
            term = hexp2(sh.laS[eW] + lT) / hlog2((float)eW + 2.f);
    }
    sh.red[t] = term;
    __syncthreads();
    for (int st = NT / 2; st > 0; st >>= 1) {
        if (t < st) sh.red[t] += sh.red[t + st];
        __syncthreads();
    }
    if (t == 0) sh.resA = sh.red[0];
    __syncthreads();
    sh.red[t] = idcg_term;
    __syncthreads();
    for (int st = NT / 2; st > 0; st >>= 1) {
        if (t < st) sh.red[t] += sh.red[t + st];
        __syncthreads();
    }
    if (t == 0) {
        const float idcg = sh.red[0];
        const bool ok = (idcg != 0.f);
        ws[2 * b + 0] = ok ? sh.resA / (idcg + EPSF) : 0.f;
        ws[2 * b + 1] = ok ? 1.f : 0.f;
    }
}

__global__ __launch_bounds__(NB) void ndcg_finalize_kernel(const float* __restrict__ ws,
                                                           float* __restrict__ out) {
    const int t = threadIdx.x;
    __shared__ float rn[NB];
    __shared__ float rc[NB];
    rn[t] = ws[2 * t + 0];
    rc[t] = ws[2 * t + 1];
    __syncthreads();
    for (int st = NB / 2; st > 0; st >>= 1) {
        if (t < st) { rn[t] += rn[t + st]; rc[t] += rc[t + st]; }
        __syncthreads();
    }
    if (t == 0) out[0] = -rn[0] / rc[0];
}

extern "C" void kernel_launch(void* const* d_in, const int* in_sizes, int n_in,
                              void* d_out, int out_size, void* d_ws, size_t ws_size,
                              hipStream_t stream) {
    const float* y_pred = (const float*)d_in[0];
    const float* y_true = (const float*)d_in[1];
    float* out = (float*)d_out;
    float* ws  = (float*)d_ws;

    ndcg_main_kernel<<<NB, NT, 0, stream>>>(y_pred, y_true, ws);
    ndcg_finalize_kernel<<<1, NB, 0, stream>>>(ws, out);
}

// Round 9
// 384.728 us; speedup vs baseline: 33.8501x; 1.0063x over previous
//
#include <hip/hip_runtime.h>
#include <math.h>

#define NB 256
#define NN 512
#define NT 1024
#define SINK_ITERS 50
#define EPSF 1e-10f
#define LOG2E 1.4426950408889634f
#define RPAD 516

typedef float v2f __attribute__((ext_vector_type(2)));

__device__ __forceinline__ float hexp2(float x) { return __builtin_amdgcn_exp2f(x); }
__device__ __forceinline__ float hlog2(float x) { return __builtin_amdgcn_logf(x); }

__device__ __forceinline__ v2f pk_fma(v2f a, v2f b, v2f c) {
    v2f d; asm("v_pk_fma_f32 %0, %1, %2, %3" : "=v"(d) : "v"(a), "v"(b), "v"(c)); return d;
}
__device__ __forceinline__ v2f pk_mul(v2f a, v2f b) {
    v2f d; asm("v_pk_mul_f32 %0, %1, %2" : "=v"(d) : "v"(a), "v"(b)); return d;
}
__device__ __forceinline__ v2f pk_add(v2f a, v2f b) {
    v2f d; asm("v_pk_add_f32 %0, %1, %2" : "=v"(d) : "v"(a), "v"(b)); return d;
}

// padded SoA indexing: element j -> word W1(j); pair c -> v2f index P2(c)
__device__ __forceinline__ int W1(int j) { return j + ((j >> 4) << 1); }
__device__ __forceinline__ int P2(int c) { return c + (c >> 3); }

struct Shm {
    __align__(16) float red2d[32][RPAD];   // 66 KB cross-tile partials
    __align__(16) v2f   xx[288];           // x_j pairs (padded)
    __align__(16) v2f   ll[288];           // lx_j pairs
    __align__(16) v2f   bb[288];           // lb_j pairs
    __align__(16) v2f   gg[288];           // lgain_j pairs
    __align__(16) float laS[NN];           // row log-scales la_i
    __align__(16) float wD[8 * 66];        // Horner coeffs deinterleaved [k][chunk]
    __align__(16) float red[NT];
    __align__(16) float sS[NN];
    __align__(16) int   cint[128];         // 4-row-group centering exponents (wave-private)
    __align__(16) int   ccint[64];         // per-8-coef-chunk centering
    int   hist[5];
    float resA;
};

// Invariant: M_ij = exp2(la_i + lb_j + i*lx_j). Row main: write per-(colgroup,row) partials.
// ll/xx hoisted to registers (iteration-invariant); only bb (+gg) read from LDS.
template<bool ADDG>
__device__ __forceinline__ void row_main(Shm& sh, int t, const v2f* llr, const v2f* xvr) {
    const int cg = t & 31;                 // column group: j in [16cg, 16cg+16)
    const int rc = t >> 5;                 // row chunk:   i in [16rc, 16rc+16)
    const float i0f = (float)(rc * 16);
    const int4 ci = *(const int4*)&sh.cint[rc * 4];
    const int c0 = ci.x, c1 = ci.y, c2 = ci.z, c3 = ci.w;

    v2f q[8];
    {
        const v2f bi = {i0f, i0f};
        const v2f bc = {-(float)c0, -(float)c0};
#pragma unroll
        for (int k = 0; k < 8; ++k) {
            const int p = P2(8 * cg + k);
            v2f lq = pk_fma(bi, llr[k], sh.bb[p]);
            lq = pk_add(lq, bc);
            if (ADDG) lq = pk_add(lq, sh.gg[p]);
            v2f qq;
            qq.x = hexp2(lq.x);            // drift-bounded by recentering: no overflow
            qq.y = hexp2(lq.y);
            q[k] = qq;
        }
    }
    float4 sbuf;
#pragma unroll
    for (int r = 0; r < 16; ++r) {
        v2f t0 = pk_add(q[0], q[1]);
        v2f t1 = pk_add(q[2], q[3]);
        v2f t2 = pk_add(q[4], q[5]);
        v2f t3 = pk_add(q[6], q[7]);
        t0 = pk_add(t0, t1);
        t2 = pk_add(t2, t3);
        t0 = pk_add(t0, t2);
        ((float*)&sbuf)[r & 3] = t0.x + t0.y;
        if ((r & 3) == 3)
            *(float4*)&sh.red2d[cg][rc * 16 + (r & ~3)] = sbuf;
        if (r < 15) {
#pragma unroll
            for (int k = 0; k < 8; ++k) q[k] = pk_mul(q[k], xvr[k]);
            if (r == 3 || r == 7 || r == 11) {
                int d = (r == 3) ? (c0 - c1) : (r == 7) ? (c1 - c2) : (c2 - c3);
                d = d < -126 ? -126 : (d > 127 ? 127 : d);
                const float f = __int_as_float((d + 127) << 23);
                const v2f f2 = {f, f};
#pragma unroll
                for (int k = 0; k < 8; ++k) q[k] = pk_mul(q[k], f2);
            }
        }
    }
}

// Phase X (barrier-free internals): reduce partials -> T_e, la_e, cint update,
// per-8 chunk centering via shfl, Horner coefficient write. Wave-local hand-offs only.
__device__ __forceinline__ void phaseX(Shm& sh, int t) {
    const int l  = t & 63;
    const int eW = ((t >> 6) << 5) + (l & 31);
    const int hW = l >> 5;

    float S = 0.f;
#pragma unroll
    for (int k = 16 * hW; k < 16 * hW + 16; ++k) S += sh.red2d[k][eW];
    S += __shfl_xor(S, 32);                // full T_e (both halves hold it)

    const float lT = hlog2(S) + (float)sh.cint[eW >> 2];   // read-before-write, same wave
    const float la = -lT;

    float mx = la;                         // max over the 8-row chunk (lanes grouped by 8)
    mx = fmaxf(mx, __shfl_xor(mx, 1));
    mx = fmaxf(mx, __shfl_xor(mx, 2));
    mx = fmaxf(mx, __shfl_xor(mx, 4));
    const int cci = (int)rintf(mx);

    if (hW == 0) {
        sh.laS[eW] = la;
        sh.wD[(eW & 7) * 66 + (eW >> 3)] = hexp2(la - (float)cci);
        if ((eW & 7) == 0) sh.ccint[eW >> 3] = cci;
        if ((eW & 3) == 0) sh.cint[eW >> 2] = (int)rintf(lT);
    }
}

// Col main: P(x_j) = sum_i exp2(la_i) x_j^i. Chunked Horner (packed) + scale-free
// accumulation: chunk value = H_c * x8m^c * 2^(cc_c + c*ex8); pre-pass finds
// B = max_c (cc_c + c*ex8); terms combined via independent ldexp + packed adds.
__device__ __forceinline__ void col_main(Shm& sh, int t, int eW, int hW,
                                         float cx, float x8m, int ex8, float clx) {
    const int chb = hW * 32;
    const int ex8_2 = ex8 + ex8;
    const int ex8_3 = ex8_2 + ex8;
    const int ex8_4 = ex8_2 + ex8_2;

    // pass 1: B = max_c (cc_c + c*ex8)   (c local to this half)
    int B = -(1 << 30);
    {
        int w0 = 0;
#pragma unroll
        for (int g = 0; g < 8; ++g) {
            const int4 cc = *(const int4*)&sh.ccint[chb + 4 * g];
            const int i0 = cc.x + w0;
            const int i1 = cc.y + w0 + ex8;
            const int i2 = cc.z + w0 + ex8_2;
            const int i3 = cc.w + w0 + ex8_3;
            B = max(B, max(max(i0, i1), max(i2, i3)));
            w0 += ex8_4;
        }
    }

    // pass 2: acc = sum_c H_c * W_c * 2^(i_c - B)
    const float x16m = x8m * x8m;          // in [1,4): plain multiplier for the W walk
    const v2f x16m2 = {x16m, x16m};
    const v2f cx2 = {cx, cx};
    v2f accA = {0.f, 0.f}, accB = {0.f, 0.f};
    v2f Wa = {1.f, x8m};                   // {x8m^(4g), x8m^(4g+1)}
    int gb = -B;                           // running cc-offset: 4g*ex8 - B
#pragma unroll
    for (int g = 0; g < 8; ++g) {
        const int c0 = chb + 4 * g;
        v2f wa[8], wb[8];
#pragma unroll
        for (int k = 0; k < 8; ++k) {
            const float4 w4 = *(const float4*)&sh.wD[k * 66 + c0];  // broadcast read
            v2f a; a.x = w4.x; a.y = w4.y; wa[k] = a;
            v2f b2; b2.x = w4.z; b2.y = w4.w; wb[k] = b2;
        }
        v2f ha = wa[7], hb = wb[7];
#pragma unroll
        for (int k = 6; k >= 0; --k) {
            ha = pk_fma(ha, cx2, wa[k]);
            hb = pk_fma(hb, cx2, wb[k]);
        }
        const int4 cc = *(const int4*)&sh.ccint[c0];
        const v2f Wb = pk_mul(Wa, x16m2);  // {x8m^(4g+2), x8m^(4g+3)}
        const v2f t1 = pk_mul(ha, Wa);
        const v2f t2 = pk_mul(hb, Wb);
        v2f u1, u2;
        u1.x = ldexpf(t1.x, cc.x + gb);
        u1.y = ldexpf(t1.y, cc.y + gb + ex8);
        u2.x = ldexpf(t2.x, cc.z + gb + ex8_2);
        u2.y = ldexpf(t2.y, cc.w + gb + ex8_3);
        accA = pk_add(accA, u1);
        accB = pk_add(accB, u2);
        Wa = pk_mul(Wb, x16m2);
        gb += ex8_4;
    }
    const v2f accT = pk_add(accA, accB);
    const float acc = accT.x + accT.y;

    float lV = hlog2(acc) + (float)B;      // acc > 0 always (B-chunk term >= 2^-90)
    if (hW) lV = fmaf(256.f, clx, lV);

    const float oV = __shfl_xor(lV, 32);   // other half, same column
    const float L = fmaxf(lV, oV), Sm = fminf(lV, oV);
    const float lb = (L < -1e30f) ? 0.f : -(L + hlog2(1.f + hexp2(Sm - L)));
    if (hW == 0) ((float*)sh.bb)[W1(eW)] = lb;
}

__global__ __launch_bounds__(NT) void ndcg_main_kernel(const float* __restrict__ y_pred,
                                                       const float* __restrict__ y_true,
                                                       float* __restrict__ ws) {
    __shared__ Shm sh;
    const int b = blockIdx.x;
    const int t = threadIdx.x;
    const int e = t & (NN - 1);
    const int hh = t >> 9;
    const int l  = t & 63;
    const int eW = ((t >> 6) << 5) + (l & 31);   // wave-local column/row index
    const int hW = l >> 5;

    // ---- pass 0: loads, histogram, R_j, SoA column tables, idcg ----
    float yt = 0.f, s = 0.f, idcg_term = 0.f;
    if (t < NN) { s = y_pred[b * NN + t]; yt = y_true[b * NN + t]; sh.sS[t] = s; }
    if (t < 5) sh.hist[t] = 0;
    __syncthreads();
    if (t < NN) {
        int vi = (int)(yt + 0.5f);
        vi = vi < 0 ? 0 : (vi > 4 ? 4 : vi);
        atomicAdd(&sh.hist[vi], 1);
    }
    const float se = sh.sS[e];
    const float4* sS4 = (const float4*)sh.sS;
    float Rp = 0.f;
#pragma unroll 8
    for (int m = hh * (NN / 8); m < (hh + 1) * (NN / 8); ++m) {
        float4 f = sS4[m];
        Rp += fabsf(se - f.x) + fabsf(se - f.y) + fabsf(se - f.z) + fabsf(se - f.w);
    }
    sh.red[t] = Rp;
    __syncthreads();                       // covers hist atomics
    if (hh == 0) {
        const float R = sh.red[t] + sh.red[t + NN];
        const float sL = se * LOG2E;
        const float lx = -2.f * sL;
        const int w = W1(e);
        ((float*)sh.xx)[w] = hexp2(lx);
        ((float*)sh.ll)[w] = lx;
        ((float*)sh.bb)[w] = fmaf(511.f, sL, -R * LOG2E);
        ((float*)sh.gg)[w] = hlog2(hexp2(yt) - 1.f);   // -inf for yt==0 (safe)
        const float dsc = 1.f / hlog2((float)e + 2.f);
        const int c4 = sh.hist[4];
        const int c3 = c4 + sh.hist[3];
        const int c2 = c3 + sh.hist[2];
        const int c1 = c2 + sh.hist[1];
        const float gp = (e < c4) ? 15.f : (e < c3) ? 7.f : (e < c2) ? 3.f :
                         (e < c1) ? 1.f : 0.f;
        idcg_term = gp * dsc;
    }
    __syncthreads();

    // persistent col-phase constants for column eW
    const float cx  = ((float*)sh.xx)[W1(eW)];
    const float clx = ((float*)sh.ll)[W1(eW)];
    const float x8f = hexp2(8.f * clx);    // |8*lx| <= ~110, no overflow
    const unsigned b8 = __float_as_uint(x8f);
    const int ex8 = (int)(b8 >> 23) - 127;
    const float x8m = __uint_as_float((b8 & 0x007FFFFFu) | 0x3F800000u);

    // persistent row-phase registers for column group (t&31): iteration-invariant
    v2f llr[8], xvr[8];
#pragma unroll
    for (int k = 0; k < 8; ++k) {
        const int p = P2(8 * (t & 31) + k);
        llr[k] = sh.ll[p];
        xvr[k] = sh.xx[p];
    }

    // ---- initial centering grid from m_i = max_j(ld_j + i*lx_j) ----
    {
        float mp = -3.4e38f;
        const v2f e2 = {(float)e, (float)e};
#pragma unroll 8
        for (int p = hh * 128; p < hh * 128 + 128; ++p) {
            const int pi = P2(p);
            v2f lq = pk_fma(e2, sh.ll[pi], sh.bb[pi]);
            mp = fmaxf(mp, fmaxf(lq.x, lq.y));
        }
        sh.red[t] = mp;
        __syncthreads();
        if (hh == 0 && (e & 3) == 0)
            sh.cint[e >> 2] = (int)rintf(fmaxf(sh.red[t], sh.red[t + NN]));
        __syncthreads();
    }

    // ---- softmax (first row normalization) ----
    row_main<false>(sh, t, llr, xvr);
    __syncthreads();
    phaseX(sh, t);
    __syncthreads();

    // ---- Sinkhorn: 50 x { col-normalize, row-normalize }, 3 barriers/iter ----
    for (int it = 0; it < SINK_ITERS; ++it) {
        col_main(sh, t, eW, hW, cx, x8m, ex8, clx);
        __syncthreads();
        row_main<false>(sh, t, llr, xvr);
        __syncthreads();
        phaseX(sh, t);
        __syncthreads();
    }

    // ---- epilogue: gains-weighted row sums ----
    row_main<true>(sh, t, llr, xvr);
    __syncthreads();
    float term = 0.f;
    {
        float S = 0.f;
#pragma unroll
        for (int k = 16 * hW; k < 16 * hW + 16; ++k) S += sh.red2d[k][eW];
        S += __shfl_xor(S, 32);
        const float lT = hlog2(S) + (float)sh.cint[eW >> 2];
        if (hW == 0)
            term = hexp2(sh.laS[eW] + lT) / hlog2((float)eW + 2.f);
    }
    sh.red[t] = term;
    __syncthreads();
    for (int st = NT / 2; st > 0; st >>= 1) {
        if (t < st) sh.red[t] += sh.red[t + st];
        __syncthreads();
    }
    if (t == 0) sh.resA = sh.red[0];
    __syncthreads();
    sh.red[t] = idcg_term;
    __syncthreads();
    for (int st = NT / 2; st > 0; st >>= 1) {
        if (t < st) sh.red[t] += sh.red[t + st];
        __syncthreads();
    }
    if (t == 0) {
        const float idcg = sh.red[0];
        const bool ok = (idcg != 0.f);
        ws[2 * b + 0] = ok ? sh.resA / (idcg + EPSF) : 0.f;
        ws[2 * b + 1] = ok ? 1.f : 0.f;
    }
}

__global__ __launch_bounds__(NB) void ndcg_finalize_kernel(const float* __restrict__ ws,
                                                           float* __restrict__ out) {
    const int t = threadIdx.x;
    __shared__ float rn[NB];
    __shared__ float rc[NB];
    rn[t] = ws[2 * t + 0];
    rc[t] = ws[2 * t + 1];
    __syncthreads();
    for (int st = NB / 2; st > 0; st >>= 1) {
        if (t < st) { rn[t] += rn[t + st]; rc[t] += rc[t + st]; }
        __syncthreads();
    }
    if (t == 0) out[0] = -rn[0] / rc[0];
}

extern "C" void kernel_launch(void* const* d_in, const int* in_sizes, int n_in,
                              void* d_out, int out_size, void* d_ws, size_t ws_size,
                              hipStream_t stream) {
    const float* y_pred = (const float*)d_in[0];
    const float* y_true = (const float*)d_in[1];
    float* out = (float*)d_out;
    float* ws  = (float*)d_ws;

    ndcg_main_kernel<<<NB, NT, 0, stream>>>(y_pred, y_true, ws);
    ndcg_finalize_kernel<<<1, NB, 0, stream>>>(ws, out);
}